// Round 25
// baseline (65.075 us; speedup 1.0000x reference)
//
#include <hip/hip_runtime.h>
#include <stdint.h>

typedef __attribute__((ext_vector_type(8))) short short8;
typedef __attribute__((ext_vector_type(4))) short short4v;
typedef __attribute__((ext_vector_type(4))) float f32x4;
typedef __attribute__((ext_vector_type(16))) float f32x16;
typedef __attribute__((ext_vector_type(4))) int i32x4;

#define B_ 8
#define C_ 64
#define N_ 4096

__device__ __forceinline__ unsigned short f2bf(float f) {
  unsigned int u = __float_as_uint(f);
  u = (u + 0x7fffu + ((u >> 16) & 1u)) >> 16;
  return (unsigned short)u;
}
// P-pack: TRUNCATING bf16 pair -> dword. 1 v_perm_b32 (r19-verified).
__device__ __forceinline__ int pk2t(float lo, float hi2) {
  return (int)__builtin_amdgcn_perm(__float_as_uint(hi2), __float_as_uint(lo),
                                    0x07060302u);
}

// Session journal: r11 fragment K/V WIN. r18 LDS tile-share WIN. r19 MFMA
// l-sum WIN. r20 paired tiles WIN. r22 qkv MFMA WIN (->64.5). r24 2 q-blocks
// per wave WIN (->62.9; flash 42.7, VGPR 100, occupancy dropped to 16% at
// 2 blocks/CU). r25: S=8 -> 1024 blocks = 4 blocks/CU = 4 waves/SIMD
// (VGPR 100 allows 5/SIMD; LDS 32KB allows 4 blocks/CU). First high-supply
// test since r18 removed the VMEM saturation that made r17's S=8 neutral.
// Banned: v_permlane32_swap_b32, v_cvt_pk_bf16_f32, lb waves beyond live set.
//
// Fragment buffers (shorts): [B][128 tiles][4 insts][64 lanes][8]
//   K: kf[b][T][f][l][j] = K[T*32+(l&31)][f*16 + (l>>5)*8 + j]
//   V: vf[b][T][g][l][j] = Vt[32*(g>>1)+(l&31)][slot T*32+(g&1)*16+(l>>5)*8+j]
//      where Vt[c][s] = v[c][sigma(s)], sigma = swap bits 2<->3 (r9-verified).

#define MFMA32(A, B, C) __builtin_amdgcn_mfma_f32_32x32x16_bf16(A, B, C, 0, 0, 0)

// ---------------- QKV projection via MFMA (byte-identical to r23/r24) ----------------
__global__ __launch_bounds__(256) void qkv_mfma(
    const float* __restrict__ x,
    const float* __restrict__ Wq, const float* __restrict__ bq,
    const float* __restrict__ Wk, const float* __restrict__ bk,
    const float* __restrict__ Wv, const float* __restrict__ bv,
    unsigned short* __restrict__ qo, unsigned short* __restrict__ kf,
    unsigned short* __restrict__ vf) {
  const int w = threadIdx.x >> 6;
  const int lane = threadIdx.x & 63;
  const int q31 = lane & 31;
  const int hi = lane >> 5;
  const int m = blockIdx.y;   // 0=q, 1=k, 2=v
  const int b = blockIdx.z;
  const int tok = blockIdx.x * 128 + w * 32 + q31;

  const f32x16 Z0 = {0.f,0.f,0.f,0.f,0.f,0.f,0.f,0.f,0.f,0.f,0.f,0.f,0.f,0.f,0.f,0.f};
  const float sc = 0.18033688011112042f;  // (1/sqrt(64))*log2(e), folded into Q

  short8 xb[4];
  const float* xcol = x + (size_t)b * C_ * N_ + tok;
#pragma unroll
  for (int ks = 0; ks < 4; ++ks) {
    short8 t;
#pragma unroll
    for (int jj = 0; jj < 8; ++jj)
      t[jj] = (short)f2bf(xcol[(size_t)(ks * 16 + hi * 8 + jj) * N_]);
    xb[ks] = t;
  }

  const float* W = (m == 0) ? Wq : (m == 1) ? Wk : Wv;
  const float* bi = (m == 0) ? bq : (m == 1) ? bk : bv;
#pragma unroll
  for (int ot = 0; ot < 2; ++ot) {
    const float* wrow = W + (ot * 32 + q31) * 64 + hi * 8;
    short8 wa0, wa1, wa2, wa3;
    {
      short8 t;
#pragma unroll
      for (int jj = 0; jj < 8; ++jj) t[jj] = (short)f2bf(wrow[jj]);
      wa0 = t;
#pragma unroll
      for (int jj = 0; jj < 8; ++jj) t[jj] = (short)f2bf(wrow[16 + jj]);
      wa1 = t;
#pragma unroll
      for (int jj = 0; jj < 8; ++jj) t[jj] = (short)f2bf(wrow[32 + jj]);
      wa2 = t;
#pragma unroll
      for (int jj = 0; jj < 8; ++jj) t[jj] = (short)f2bf(wrow[48 + jj]);
      wa3 = t;
    }
    f32x16 acc = MFMA32(wa0, xb[0], Z0);
    acc = MFMA32(wa1, xb[1], acc);
    acc = MFMA32(wa2, xb[2], acc);
    acc = MFMA32(wa3, xb[3], acc);

    if (m == 0) {
      unsigned short* dst = qo + ((size_t)b * N_ + tok) * 64;
#pragma unroll
      for (int g = 0; g < 4; ++g) {
        const int ob = 8 * g + 4 * hi + 32 * ot;
        short4v res;
#pragma unroll
        for (int i = 0; i < 4; ++i)
          res[i] = (short)f2bf((acc[4 * g + i] + bi[ob + i]) * sc);
        *(short4v*)(dst + ob) = res;
      }
    } else if (m == 1) {
      const int T = tok >> 5;
      unsigned short* kb_ = kf + (size_t)b * N_ * 64;
#pragma unroll
      for (int g = 0; g < 4; ++g) {
        const int ob = 8 * g + 4 * hi + 32 * ot;
        const int f = ob >> 4;
        const int l = (tok & 31) + 32 * ((ob >> 3) & 1);
        short4v res;
#pragma unroll
        for (int i = 0; i < 4; ++i)
          res[i] = (short)f2bf(acc[4 * g + i] + bi[ob + i]);
        *(short4v*)(kb_ + ((size_t)T * 4 + f) * 512 + l * 8 + (ob & 7)) = res;
      }
    } else {
      const int piece = (tok >> 5) * 4 + ot * 2 + ((tok >> 4) & 1);
      const int jv = (tok & 3) | (((tok >> 3) & 1) << 2);
      const int lb32 = 32 * ((tok >> 2) & 1);
      unsigned short* vbase = vf + (size_t)b * N_ * 64 + (size_t)piece * 512 + jv;
#pragma unroll
      for (int r = 0; r < 16; ++r) {
        const int o31 = (r & 3) + 8 * (r >> 2) + 4 * hi;
        vbase[(o31 + lb32) * 8] = f2bf(acc[r] + bi[o31 + 32 * ot]);
      }
    }
  }
}

// ---------------- Flash attention: 2 q-blocks per wave (r24), S=8 supply ----------------
#define GLDS(SRC, DST) \
  __builtin_amdgcn_global_load_lds( \
      (const __attribute__((address_space(1))) unsigned int*)(SRC), \
      (__attribute__((address_space(3))) unsigned int*)(DST), 16, 0, 0)

#define STAGE2(SET, TA, TB) { \
  GLDS(kb + (size_t)(TA) * 2048 + w * 512 + lane * 8, &lK[SET][0][w * 512]); \
  GLDS(vb + (size_t)(TA) * 2048 + w * 512 + lane * 8, &lV[SET][0][w * 512]); \
  GLDS(kb + (size_t)(TB) * 2048 + w * 512 + lane * 8, &lK[SET][1][w * 512]); \
  GLDS(vb + (size_t)(TB) * 2048 + w * 512 + lane * 8, &lV[SET][1][w * 512]); \
}

#define LDSK(KF, SET, P) { \
  const unsigned short* kr_ = &lK[SET][P][lane * 8]; \
  KF##0 = *(const short8*)(kr_);        KF##1 = *(const short8*)(kr_ + 512); \
  KF##2 = *(const short8*)(kr_ + 1024); KF##3 = *(const short8*)(kr_ + 1536); }

#define LDSV(VF, SET, P) { \
  const unsigned short* vr_ = &lV[SET][P][lane * 8]; \
  VF##0 = *(const short8*)(vr_);        VF##1 = *(const short8*)(vr_ + 512); \
  VF##2 = *(const short8*)(vr_ + 1024); VF##3 = *(const short8*)(vr_ + 1536); }

#define S_PHASE(S, KF, QF) do { \
  S = MFMA32(KF##0, QF##0, Z0); \
  S = MFMA32(KF##1, QF##1, S); \
  S = MFMA32(KF##2, QF##2, S); \
  S = MFMA32(KF##3, QF##3, S); \
} while (0)

#define SMPV(S, VF, O0, O1, LS) do { \
  _Pragma("unroll") \
  for (int r_ = 0; r_ < 16; ++r_) S[r_] = __builtin_amdgcn_exp2f(S[r_]); \
  const short8 P0 = __builtin_bit_cast(short8, \
      (i32x4){pk2t(S[0], S[1]), pk2t(S[2], S[3]), pk2t(S[4], S[5]), pk2t(S[6], S[7])}); \
  const short8 P1 = __builtin_bit_cast(short8, \
      (i32x4){pk2t(S[8], S[9]), pk2t(S[10], S[11]), pk2t(S[12], S[13]), pk2t(S[14], S[15])}); \
  LS = MFMA32(ONES, P0, LS); LS = MFMA32(ONES, P1, LS); \
  O0 = MFMA32(VF##0, P0, O0); O0 = MFMA32(VF##1, P1, O0); \
  O1 = MFMA32(VF##2, P0, O1); O1 = MFMA32(VF##3, P1, O1); \
} while (0)

__global__ __launch_bounds__(256, 2) void flash_attn2(
    const unsigned short* __restrict__ q,
    const unsigned short* __restrict__ kf,
    const unsigned short* __restrict__ vf,
    float* __restrict__ out,
    unsigned short* __restrict__ po, float* __restrict__ pl,
    int nsplit, int tiles) {
  const int b = blockIdx.x & 7;        // batch -> XCD pinning (L2 locality)
  const int j = blockIdx.x >> 3;
  const int w = threadIdx.x >> 6;
  const int item = j * 4 + w;          // [0, 64*nsplit); 4 waves of a block
  const int p = item & 63;             //   share split, consecutive q-pair
  const int split = item >> 6;
  const int lane = threadIdx.x & 63;
  const int q31 = lane & 31;
  const int hi = lane >> 5;

  __shared__ __align__(16) unsigned short lK[2][2][2048];  // 2 sets x 2-tile pairs
  __shared__ __align__(16) unsigned short lV[2][2][2048];

  // Two Q fragment sets: rows [p*64, p*64+32) and [p*64+32, p*64+64)
  const unsigned short* qpA = q + ((size_t)b * N_ + p * 64 + q31) * 64 + hi * 8;
  short8 qfA0 = *(const short8*)(qpA);
  short8 qfA1 = *(const short8*)(qpA + 16);
  short8 qfA2 = *(const short8*)(qpA + 32);
  short8 qfA3 = *(const short8*)(qpA + 48);
  const unsigned short* qpB = qpA + (size_t)32 * 64;
  short8 qfB0 = *(const short8*)(qpB);
  short8 qfB1 = *(const short8*)(qpB + 16);
  short8 qfB2 = *(const short8*)(qpB + 32);
  short8 qfB3 = *(const short8*)(qpB + 48);

  const short one_ = (short)0x3F80;  // bf16 1.0
  const short8 ONES = (short8){one_, one_, one_, one_, one_, one_, one_, one_};
  const f32x16 Z0 = {0.f,0.f,0.f,0.f,0.f,0.f,0.f,0.f,0.f,0.f,0.f,0.f,0.f,0.f,0.f,0.f};

  const unsigned short* kb = kf + (size_t)b * N_ * 64;
  const unsigned short* vb = vf + (size_t)b * N_ * 64;

  f32x16 o0A = Z0, o1A = Z0, lsA = Z0;
  f32x16 o0B = Z0, o1B = Z0, lsB = Z0;
  f32x16 s;

  short8 kA0, kA1, kA2, kA3;
  short8 vA0, vA1, vA2, vA3;

  const int t0 = split * tiles, t1 = t0 + tiles;  // tiles even (16 at S=8)
  STAGE2(0, t0, t0 + 1);
  __syncthreads();  // pre-barrier vmcnt(0) drain completes the stage
  for (int t = t0; t < t1; t += 2) {
    const int cur = ((t - t0) >> 1) & 1;
    if (t + 2 < t1) STAGE2(cur ^ 1, t + 2, t + 3);  // in flight under this pair
#pragma unroll
    for (int P = 0; P < 2; ++P) {
      LDSK(kA, cur, P);
      LDSV(vA, cur, P);
      S_PHASE(s, kA, qfA);               // K/V fragments reused for both q-blocks
      SMPV(s, vA, o0A, o1A, lsA);
      S_PHASE(s, kA, qfB);
      SMPV(s, vA, o0B, o1B, lsB);
    }
    __syncthreads();  // all waves done with cur; staged cur^1 drained
  }

  const int nA = p * 64 + q31;
  const int nB = nA + 32;
  if (nsplit == 1) {
    const float invA = 1.f / lsA[0], invB = 1.f / lsB[0];
    float* ob = out + (size_t)b * 64 * N_;
#pragma unroll
    for (int r_ = 0; r_ < 16; ++r_) {
      const int cl = (r_ & 3) + 8 * (r_ >> 2) + 4 * hi;
      ob[(size_t)cl * N_ + nA] = o0A[r_] * invA;
      ob[(size_t)(cl + 32) * N_ + nA] = o1A[r_] * invA;
      ob[(size_t)cl * N_ + nB] = o0B[r_] * invB;
      ob[(size_t)(cl + 32) * N_ + nB] = o1B[r_] * invB;
    }
  } else {
    // partials: po[split][b][c][n] unnormalized bf16; pl[split][b][n] fp32
    unsigned short* pr = po + ((size_t)(split * B_ + b) * 64) * N_;
#pragma unroll
    for (int r_ = 0; r_ < 16; ++r_) {
      const int cl = (r_ & 3) + 8 * (r_ >> 2) + 4 * hi;
      pr[(size_t)cl * N_ + nA] = f2bf(o0A[r_]);
      pr[(size_t)(cl + 32) * N_ + nA] = f2bf(o1A[r_]);
      pr[(size_t)cl * N_ + nB] = f2bf(o0B[r_]);
      pr[(size_t)(cl + 32) * N_ + nB] = f2bf(o1B[r_]);
    }
    if (hi == 0) {
      pl[(size_t)(split * B_ + b) * N_ + nA] = lsA[0];
      pl[(size_t)(split * B_ + b) * N_ + nB] = lsB[0];
    }
  }
}

// ---------------- Combine partials: plain sum, 2-n vectorized (r21) ----------------
template <int NS>
__global__ __launch_bounds__(256) void combine_k(
    const unsigned short* __restrict__ po, const float* __restrict__ pl,
    float* __restrict__ out) {
  const int n2 = (blockIdx.x * 256 + threadIdx.x) * 2;  // grid.x = N_/512
  const int c0 = blockIdx.y * 8;                        // grid.y = 8
  const int b = blockIdx.z;
  const size_t sb = (size_t)B_ * N_;

  float l0 = 0.f, l1 = 0.f;
#pragma unroll
  for (int s = 0; s < NS; ++s) {
    const float2 pv = *(const float2*)(pl + s * sb + (size_t)b * N_ + n2);
    l0 += pv.x; l1 += pv.y;
  }
  const float inv0 = 1.f / l0, inv1 = 1.f / l1;

#pragma unroll
  for (int cc = 0; cc < 8; ++cc) {
    float a0 = 0.f, a1 = 0.f;
#pragma unroll
    for (int s = 0; s < NS; ++s) {
      const unsigned v = *(const unsigned*)(
          po + ((size_t)(s * B_ + b) * 64 + c0 + cc) * N_ + n2);
      a0 += __uint_as_float(v << 16);
      a1 += __uint_as_float(v & 0xFFFF0000u);
    }
    float2 r;
    r.x = a0 * inv0; r.y = a1 * inv1;
    *(float2*)(out + ((size_t)b * 64 + c0 + cc) * N_ + n2) = r;
  }
}

extern "C" void kernel_launch(void* const* d_in, const int* in_sizes, int n_in,
                              void* d_out, int out_size, void* d_ws, size_t ws_size,
                              hipStream_t stream) {
  const float* x  = (const float*)d_in[0];
  const float* Wq = (const float*)d_in[1];
  const float* bq = (const float*)d_in[2];
  const float* Wk = (const float*)d_in[3];
  const float* bk = (const float*)d_in[4];
  const float* Wv = (const float*)d_in[5];
  const float* bv = (const float*)d_in[6];
  float* out = (float*)d_out;

  unsigned short* qws = (unsigned short*)d_ws;          // [B][N][64] bf16 row-major (scaled)
  unsigned short* kws = qws + (size_t)B_ * N_ * 64;     // [B][128][4][64][8] bf16 fragments
  unsigned short* vws = kws + (size_t)B_ * N_ * 64;     // [B][128][4][64][8] bf16 fragments

  const size_t qkv_bytes = (size_t)3 * B_ * N_ * 64 * 2;                          // 12 MB
  const size_t per_split = (size_t)B_ * N_ * 64 * 2 + (size_t)B_ * N_ * 4;        // 4.125 MB

  // S=8: 1024 blocks = 4 blocks/CU (LDS-limited) = 16 waves/CU = 4 waves/SIMD
  // at VGPR=100 (HW cap 5/SIMD). First high-supply test post-r18 LDS staging.
  int S = 1;
  if (ws_size >= qkv_bytes + 8 * per_split) S = 8;
  else if (ws_size >= qkv_bytes + 4 * per_split) S = 4;
  else if (ws_size >= qkv_bytes + 2 * per_split) S = 2;

  unsigned short* po = (unsigned short*)((char*)d_ws + qkv_bytes);  // [S][B][64][N] bf16
  float* pl = (float*)(po + (size_t)S * B_ * N_ * 64);              // [S][B][N] fp32

  qkv_mfma<<<dim3(N_ / 128, 3, B_), 256, 0, stream>>>(
      x, Wq, bq, Wk, bk, Wv, bv, qws, kws, vws);

  flash_attn2<<<128 * S, 256, 0, stream>>>(qws, kws, vws, out, po, pl, S, 128 / S);

  if (S == 8)      combine_k<8><<<dim3(N_ / 512, 8, B_), 256, 0, stream>>>(po, pl, out);
  else if (S == 4) combine_k<4><<<dim3(N_ / 512, 8, B_), 256, 0, stream>>>(po, pl, out);
  else if (S == 2) combine_k<2><<<dim3(N_ / 512, 8, B_), 256, 0, stream>>>(po, pl, out);
}

// Round 26
// 62.363 us; speedup vs baseline: 1.0435x; 1.0435x over previous
//
#include <hip/hip_runtime.h>
#include <stdint.h>

typedef __attribute__((ext_vector_type(8))) short short8;
typedef __attribute__((ext_vector_type(4))) short short4v;
typedef __attribute__((ext_vector_type(4))) float f32x4;
typedef __attribute__((ext_vector_type(16))) float f32x16;
typedef __attribute__((ext_vector_type(4))) int i32x4;

#define B_ 8
#define C_ 64
#define N_ 4096

__device__ __forceinline__ unsigned short f2bf(float f) {
  unsigned int u = __float_as_uint(f);
  u = (u + 0x7fffu + ((u >> 16) & 1u)) >> 16;
  return (unsigned short)u;
}
// P-pack: TRUNCATING bf16 pair -> dword. 1 v_perm_b32 (r19-verified).
__device__ __forceinline__ int pk2t(float lo, float hi2) {
  return (int)__builtin_amdgcn_perm(__float_as_uint(hi2), __float_as_uint(lo),
                                    0x07060302u);
}

// Session journal: r11 fragment K/V WIN. r18 LDS tile-share WIN. r19 MFMA
// l-sum WIN. r20 2-tiles/barrier WIN. r22 qkv MFMA WIN. r24 2 q-blocks/wave
// WIN (62.9 best; flash 42.7, VGPR 100). r25 S=8 REGRESSION (occupancy pinned
// by VGPR step at 16 waves/CU; only added overhead+combine traffic) ->
// reverted to S=4. r26: 4 tiles/barrier (barriers 16->8/wave, LDS 64KB,
// 2 blocks/CU unchanged — residency is VGPR-bound not LDS-bound).
// Banned: v_permlane32_swap_b32, v_cvt_pk_bf16_f32, lb waves beyond live set.
//
// Fragment buffers (shorts): [B][128 tiles][4 insts][64 lanes][8]
//   K: kf[b][T][f][l][j] = K[T*32+(l&31)][f*16 + (l>>5)*8 + j]
//   V: vf[b][T][g][l][j] = Vt[32*(g>>1)+(l&31)][slot T*32+(g&1)*16+(l>>5)*8+j]
//      where Vt[c][s] = v[c][sigma(s)], sigma = swap bits 2<->3 (r9-verified).

#define MFMA32(A, B, C) __builtin_amdgcn_mfma_f32_32x32x16_bf16(A, B, C, 0, 0, 0)

// ---------------- QKV projection via MFMA (byte-identical to r23/r24) ----------------
__global__ __launch_bounds__(256) void qkv_mfma(
    const float* __restrict__ x,
    const float* __restrict__ Wq, const float* __restrict__ bq,
    const float* __restrict__ Wk, const float* __restrict__ bk,
    const float* __restrict__ Wv, const float* __restrict__ bv,
    unsigned short* __restrict__ qo, unsigned short* __restrict__ kf,
    unsigned short* __restrict__ vf) {
  const int w = threadIdx.x >> 6;
  const int lane = threadIdx.x & 63;
  const int q31 = lane & 31;
  const int hi = lane >> 5;
  const int m = blockIdx.y;   // 0=q, 1=k, 2=v
  const int b = blockIdx.z;
  const int tok = blockIdx.x * 128 + w * 32 + q31;

  const f32x16 Z0 = {0.f,0.f,0.f,0.f,0.f,0.f,0.f,0.f,0.f,0.f,0.f,0.f,0.f,0.f,0.f,0.f};
  const float sc = 0.18033688011112042f;  // (1/sqrt(64))*log2(e), folded into Q

  short8 xb[4];
  const float* xcol = x + (size_t)b * C_ * N_ + tok;
#pragma unroll
  for (int ks = 0; ks < 4; ++ks) {
    short8 t;
#pragma unroll
    for (int jj = 0; jj < 8; ++jj)
      t[jj] = (short)f2bf(xcol[(size_t)(ks * 16 + hi * 8 + jj) * N_]);
    xb[ks] = t;
  }

  const float* W = (m == 0) ? Wq : (m == 1) ? Wk : Wv;
  const float* bi = (m == 0) ? bq : (m == 1) ? bk : bv;
#pragma unroll
  for (int ot = 0; ot < 2; ++ot) {
    const float* wrow = W + (ot * 32 + q31) * 64 + hi * 8;
    short8 wa0, wa1, wa2, wa3;
    {
      short8 t;
#pragma unroll
      for (int jj = 0; jj < 8; ++jj) t[jj] = (short)f2bf(wrow[jj]);
      wa0 = t;
#pragma unroll
      for (int jj = 0; jj < 8; ++jj) t[jj] = (short)f2bf(wrow[16 + jj]);
      wa1 = t;
#pragma unroll
      for (int jj = 0; jj < 8; ++jj) t[jj] = (short)f2bf(wrow[32 + jj]);
      wa2 = t;
#pragma unroll
      for (int jj = 0; jj < 8; ++jj) t[jj] = (short)f2bf(wrow[48 + jj]);
      wa3 = t;
    }
    f32x16 acc = MFMA32(wa0, xb[0], Z0);
    acc = MFMA32(wa1, xb[1], acc);
    acc = MFMA32(wa2, xb[2], acc);
    acc = MFMA32(wa3, xb[3], acc);

    if (m == 0) {
      unsigned short* dst = qo + ((size_t)b * N_ + tok) * 64;
#pragma unroll
      for (int g = 0; g < 4; ++g) {
        const int ob = 8 * g + 4 * hi + 32 * ot;
        short4v res;
#pragma unroll
        for (int i = 0; i < 4; ++i)
          res[i] = (short)f2bf((acc[4 * g + i] + bi[ob + i]) * sc);
        *(short4v*)(dst + ob) = res;
      }
    } else if (m == 1) {
      const int T = tok >> 5;
      unsigned short* kb_ = kf + (size_t)b * N_ * 64;
#pragma unroll
      for (int g = 0; g < 4; ++g) {
        const int ob = 8 * g + 4 * hi + 32 * ot;
        const int f = ob >> 4;
        const int l = (tok & 31) + 32 * ((ob >> 3) & 1);
        short4v res;
#pragma unroll
        for (int i = 0; i < 4; ++i)
          res[i] = (short)f2bf(acc[4 * g + i] + bi[ob + i]);
        *(short4v*)(kb_ + ((size_t)T * 4 + f) * 512 + l * 8 + (ob & 7)) = res;
      }
    } else {
      const int piece = (tok >> 5) * 4 + ot * 2 + ((tok >> 4) & 1);
      const int jv = (tok & 3) | (((tok >> 3) & 1) << 2);
      const int lb32 = 32 * ((tok >> 2) & 1);
      unsigned short* vbase = vf + (size_t)b * N_ * 64 + (size_t)piece * 512 + jv;
#pragma unroll
      for (int r = 0; r < 16; ++r) {
        const int o31 = (r & 3) + 8 * (r >> 2) + 4 * hi;
        vbase[(o31 + lb32) * 8] = f2bf(acc[r] + bi[o31 + 32 * ot]);
      }
    }
  }
}

// ---------------- Flash attention: 2 q-blocks per wave, 4 tiles per barrier ----------------
#define GLDS(SRC, DST) \
  __builtin_amdgcn_global_load_lds( \
      (const __attribute__((address_space(1))) unsigned int*)(SRC), \
      (__attribute__((address_space(3))) unsigned int*)(DST), 16, 0, 0)

#define STAGE1(SET, SLOT, T) { \
  GLDS(kb + (size_t)(T) * 2048 + w * 512 + lane * 8, &lK[SET][SLOT][w * 512]); \
  GLDS(vb + (size_t)(T) * 2048 + w * 512 + lane * 8, &lV[SET][SLOT][w * 512]); \
}

#define STAGE4(SET, T) { \
  STAGE1(SET, 0, (T));     STAGE1(SET, 1, (T) + 1); \
  STAGE1(SET, 2, (T) + 2); STAGE1(SET, 3, (T) + 3); \
}

#define LDSK(KF, SET, P) { \
  const unsigned short* kr_ = &lK[SET][P][lane * 8]; \
  KF##0 = *(const short8*)(kr_);        KF##1 = *(const short8*)(kr_ + 512); \
  KF##2 = *(const short8*)(kr_ + 1024); KF##3 = *(const short8*)(kr_ + 1536); }

#define LDSV(VF, SET, P) { \
  const unsigned short* vr_ = &lV[SET][P][lane * 8]; \
  VF##0 = *(const short8*)(vr_);        VF##1 = *(const short8*)(vr_ + 512); \
  VF##2 = *(const short8*)(vr_ + 1024); VF##3 = *(const short8*)(vr_ + 1536); }

#define S_PHASE(S, KF, QF) do { \
  S = MFMA32(KF##0, QF##0, Z0); \
  S = MFMA32(KF##1, QF##1, S); \
  S = MFMA32(KF##2, QF##2, S); \
  S = MFMA32(KF##3, QF##3, S); \
} while (0)

#define SMPV(S, VF, O0, O1, LS) do { \
  _Pragma("unroll") \
  for (int r_ = 0; r_ < 16; ++r_) S[r_] = __builtin_amdgcn_exp2f(S[r_]); \
  const short8 P0 = __builtin_bit_cast(short8, \
      (i32x4){pk2t(S[0], S[1]), pk2t(S[2], S[3]), pk2t(S[4], S[5]), pk2t(S[6], S[7])}); \
  const short8 P1 = __builtin_bit_cast(short8, \
      (i32x4){pk2t(S[8], S[9]), pk2t(S[10], S[11]), pk2t(S[12], S[13]), pk2t(S[14], S[15])}); \
  LS = MFMA32(ONES, P0, LS); LS = MFMA32(ONES, P1, LS); \
  O0 = MFMA32(VF##0, P0, O0); O0 = MFMA32(VF##1, P1, O0); \
  O1 = MFMA32(VF##2, P0, O1); O1 = MFMA32(VF##3, P1, O1); \
} while (0)

__global__ __launch_bounds__(256, 2) void flash_attn2(
    const unsigned short* __restrict__ q,
    const unsigned short* __restrict__ kf,
    const unsigned short* __restrict__ vf,
    float* __restrict__ out,
    unsigned short* __restrict__ po, float* __restrict__ pl,
    int nsplit, int tiles) {
  const int b = blockIdx.x & 7;        // batch -> XCD pinning (L2 locality)
  const int j = blockIdx.x >> 3;
  const int w = threadIdx.x >> 6;
  const int item = j * 4 + w;          // [0, 64*nsplit); 4 waves of a block
  const int p = item & 63;             //   share split, consecutive q-pair
  const int split = item >> 6;
  const int lane = threadIdx.x & 63;
  const int q31 = lane & 31;
  const int hi = lane >> 5;

  __shared__ __align__(16) unsigned short lK[2][4][2048];  // 2 sets x 4-tile groups
  __shared__ __align__(16) unsigned short lV[2][4][2048];  // 64KB total

  // Two Q fragment sets: rows [p*64, p*64+32) and [p*64+32, p*64+64)
  const unsigned short* qpA = q + ((size_t)b * N_ + p * 64 + q31) * 64 + hi * 8;
  short8 qfA0 = *(const short8*)(qpA);
  short8 qfA1 = *(const short8*)(qpA + 16);
  short8 qfA2 = *(const short8*)(qpA + 32);
  short8 qfA3 = *(const short8*)(qpA + 48);
  const unsigned short* qpB = qpA + (size_t)32 * 64;
  short8 qfB0 = *(const short8*)(qpB);
  short8 qfB1 = *(const short8*)(qpB + 16);
  short8 qfB2 = *(const short8*)(qpB + 32);
  short8 qfB3 = *(const short8*)(qpB + 48);

  const short one_ = (short)0x3F80;  // bf16 1.0
  const short8 ONES = (short8){one_, one_, one_, one_, one_, one_, one_, one_};
  const f32x16 Z0 = {0.f,0.f,0.f,0.f,0.f,0.f,0.f,0.f,0.f,0.f,0.f,0.f,0.f,0.f,0.f,0.f};

  const unsigned short* kb = kf + (size_t)b * N_ * 64;
  const unsigned short* vb = vf + (size_t)b * N_ * 64;

  f32x16 o0A = Z0, o1A = Z0, lsA = Z0;
  f32x16 o0B = Z0, o1B = Z0, lsB = Z0;
  f32x16 s;

  short8 kA0, kA1, kA2, kA3;
  short8 vA0, vA1, vA2, vA3;

  const int t0 = split * tiles, t1 = t0 + tiles;  // tiles % 4 == 0 (32 at S=4)
  STAGE4(0, t0);
  __syncthreads();  // pre-barrier vmcnt(0) drain completes the stage
  for (int t = t0; t < t1; t += 4) {
    const int cur = ((t - t0) >> 2) & 1;
    if (t + 4 < t1) STAGE4(cur ^ 1, t + 4);  // in flight under this group
#pragma unroll
    for (int P = 0; P < 4; ++P) {
      LDSK(kA, cur, P);
      LDSV(vA, cur, P);
      S_PHASE(s, kA, qfA);               // K/V fragments reused for both q-blocks
      SMPV(s, vA, o0A, o1A, lsA);
      S_PHASE(s, kA, qfB);
      SMPV(s, vA, o0B, o1B, lsB);
    }
    __syncthreads();  // all waves done with cur; staged cur^1 drained
  }

  const int nA = p * 64 + q31;
  const int nB = nA + 32;
  if (nsplit == 1) {
    const float invA = 1.f / lsA[0], invB = 1.f / lsB[0];
    float* ob = out + (size_t)b * 64 * N_;
#pragma unroll
    for (int r_ = 0; r_ < 16; ++r_) {
      const int cl = (r_ & 3) + 8 * (r_ >> 2) + 4 * hi;
      ob[(size_t)cl * N_ + nA] = o0A[r_] * invA;
      ob[(size_t)(cl + 32) * N_ + nA] = o1A[r_] * invA;
      ob[(size_t)cl * N_ + nB] = o0B[r_] * invB;
      ob[(size_t)(cl + 32) * N_ + nB] = o1B[r_] * invB;
    }
  } else {
    // partials: po[split][b][c][n] unnormalized bf16; pl[split][b][n] fp32
    unsigned short* pr = po + ((size_t)(split * B_ + b) * 64) * N_;
#pragma unroll
    for (int r_ = 0; r_ < 16; ++r_) {
      const int cl = (r_ & 3) + 8 * (r_ >> 2) + 4 * hi;
      pr[(size_t)cl * N_ + nA] = f2bf(o0A[r_]);
      pr[(size_t)(cl + 32) * N_ + nA] = f2bf(o1A[r_]);
      pr[(size_t)cl * N_ + nB] = f2bf(o0B[r_]);
      pr[(size_t)(cl + 32) * N_ + nB] = f2bf(o1B[r_]);
    }
    if (hi == 0) {
      pl[(size_t)(split * B_ + b) * N_ + nA] = lsA[0];
      pl[(size_t)(split * B_ + b) * N_ + nB] = lsB[0];
    }
  }
}

// ---------------- Combine partials: plain sum, 2-n vectorized (r21) ----------------
template <int NS>
__global__ __launch_bounds__(256) void combine_k(
    const unsigned short* __restrict__ po, const float* __restrict__ pl,
    float* __restrict__ out) {
  const int n2 = (blockIdx.x * 256 + threadIdx.x) * 2;  // grid.x = N_/512
  const int c0 = blockIdx.y * 8;                        // grid.y = 8
  const int b = blockIdx.z;
  const size_t sb = (size_t)B_ * N_;

  float l0 = 0.f, l1 = 0.f;
#pragma unroll
  for (int s = 0; s < NS; ++s) {
    const float2 pv = *(const float2*)(pl + s * sb + (size_t)b * N_ + n2);
    l0 += pv.x; l1 += pv.y;
  }
  const float inv0 = 1.f / l0, inv1 = 1.f / l1;

#pragma unroll
  for (int cc = 0; cc < 8; ++cc) {
    float a0 = 0.f, a1 = 0.f;
#pragma unroll
    for (int s = 0; s < NS; ++s) {
      const unsigned v = *(const unsigned*)(
          po + ((size_t)(s * B_ + b) * 64 + c0 + cc) * N_ + n2);
      a0 += __uint_as_float(v << 16);
      a1 += __uint_as_float(v & 0xFFFF0000u);
    }
    float2 r;
    r.x = a0 * inv0; r.y = a1 * inv1;
    *(float2*)(out + ((size_t)b * 64 + c0 + cc) * N_ + n2) = r;
  }
}

extern "C" void kernel_launch(void* const* d_in, const int* in_sizes, int n_in,
                              void* d_out, int out_size, void* d_ws, size_t ws_size,
                              hipStream_t stream) {
  const float* x  = (const float*)d_in[0];
  const float* Wq = (const float*)d_in[1];
  const float* bq = (const float*)d_in[2];
  const float* Wk = (const float*)d_in[3];
  const float* bk = (const float*)d_in[4];
  const float* Wv = (const float*)d_in[5];
  const float* bv = (const float*)d_in[6];
  float* out = (float*)d_out;

  unsigned short* qws = (unsigned short*)d_ws;          // [B][N][64] bf16 row-major (scaled)
  unsigned short* kws = qws + (size_t)B_ * N_ * 64;     // [B][128][4][64][8] bf16 fragments
  unsigned short* vws = kws + (size_t)B_ * N_ * 64;     // [B][128][4][64][8] bf16 fragments

  const size_t qkv_bytes = (size_t)3 * B_ * N_ * 64 * 2;                          // 12 MB
  const size_t per_split = (size_t)B_ * N_ * 64 * 2 + (size_t)B_ * N_ * 4;        // 4.125 MB

  // S=4 (r24 best config; r25 showed S=8 regresses — residency is VGPR-capped).
  int S = 1;
  if (ws_size >= qkv_bytes + 4 * per_split) S = 4;
  else if (ws_size >= qkv_bytes + 2 * per_split) S = 2;

  unsigned short* po = (unsigned short*)((char*)d_ws + qkv_bytes);  // [S][B][64][N] bf16
  float* pl = (float*)(po + (size_t)S * B_ * N_ * 64);              // [S][B][N] fp32

  qkv_mfma<<<dim3(N_ / 128, 3, B_), 256, 0, stream>>>(
      x, Wq, bq, Wk, bk, Wv, bv, qws, kws, vws);

  flash_attn2<<<128 * S, 256, 0, stream>>>(qws, kws, vws, out, po, pl, S, 128 / S);

  if (S == 4)      combine_k<4><<<dim3(N_ / 512, 8, B_), 256, 0, stream>>>(po, pl, out);
  else if (S == 2) combine_k<2><<<dim3(N_ / 512, 8, B_), 256, 0, stream>>>(po, pl, out);
}

// Round 27
// 62.302 us; speedup vs baseline: 1.0445x; 1.0010x over previous
//
#include <hip/hip_runtime.h>
#include <stdint.h>

typedef __attribute__((ext_vector_type(8))) short short8;
typedef __attribute__((ext_vector_type(4))) short short4v;
typedef __attribute__((ext_vector_type(4))) float f32x4;
typedef __attribute__((ext_vector_type(16))) float f32x16;
typedef __attribute__((ext_vector_type(4))) int i32x4;

#define B_ 8
#define C_ 64
#define N_ 4096

__device__ __forceinline__ unsigned short f2bf(float f) {
  unsigned int u = __float_as_uint(f);
  u = (u + 0x7fffu + ((u >> 16) & 1u)) >> 16;
  return (unsigned short)u;
}
// P-pack: TRUNCATING bf16 pair -> dword. 1 v_perm_b32 (r19-verified).
__device__ __forceinline__ int pk2t(float lo, float hi2) {
  return (int)__builtin_amdgcn_perm(__float_as_uint(hi2), __float_as_uint(lo),
                                    0x07060302u);
}

// Session journal: r11 fragment K/V WIN. r18 LDS tile-share WIN. r19 MFMA
// l-sum WIN. r20 2-tiles/barrier WIN. r22 qkv MFMA WIN. r24 2 q-blocks/wave
// WIN. r25 S=8 REGRESSION (VGPR-capped residency). r26 4-tiles/barrier WIN
// (62.4 best; flash 41.8). r27: explicit 2-stream ILP — S_PHASE(A);
// S_PHASE(B); SMPV(A); SMPV(B) with two live score tiles (+16 VGPR, same
// residency bracket): B's MFMA chain completes under A's softmax VALU.
// Banned: v_permlane32_swap_b32, v_cvt_pk_bf16_f32, lb waves beyond live set.
//
// Fragment buffers (shorts): [B][128 tiles][4 insts][64 lanes][8]
//   K: kf[b][T][f][l][j] = K[T*32+(l&31)][f*16 + (l>>5)*8 + j]
//   V: vf[b][T][g][l][j] = Vt[32*(g>>1)+(l&31)][slot T*32+(g&1)*16+(l>>5)*8+j]
//      where Vt[c][s] = v[c][sigma(s)], sigma = swap bits 2<->3 (r9-verified).

#define MFMA32(A, B, C) __builtin_amdgcn_mfma_f32_32x32x16_bf16(A, B, C, 0, 0, 0)

// ---------------- QKV projection via MFMA (byte-identical to r23-r26) ----------------
__global__ __launch_bounds__(256) void qkv_mfma(
    const float* __restrict__ x,
    const float* __restrict__ Wq, const float* __restrict__ bq,
    const float* __restrict__ Wk, const float* __restrict__ bk,
    const float* __restrict__ Wv, const float* __restrict__ bv,
    unsigned short* __restrict__ qo, unsigned short* __restrict__ kf,
    unsigned short* __restrict__ vf) {
  const int w = threadIdx.x >> 6;
  const int lane = threadIdx.x & 63;
  const int q31 = lane & 31;
  const int hi = lane >> 5;
  const int m = blockIdx.y;   // 0=q, 1=k, 2=v
  const int b = blockIdx.z;
  const int tok = blockIdx.x * 128 + w * 32 + q31;

  const f32x16 Z0 = {0.f,0.f,0.f,0.f,0.f,0.f,0.f,0.f,0.f,0.f,0.f,0.f,0.f,0.f,0.f,0.f};
  const float sc = 0.18033688011112042f;  // (1/sqrt(64))*log2(e), folded into Q

  short8 xb[4];
  const float* xcol = x + (size_t)b * C_ * N_ + tok;
#pragma unroll
  for (int ks = 0; ks < 4; ++ks) {
    short8 t;
#pragma unroll
    for (int jj = 0; jj < 8; ++jj)
      t[jj] = (short)f2bf(xcol[(size_t)(ks * 16 + hi * 8 + jj) * N_]);
    xb[ks] = t;
  }

  const float* W = (m == 0) ? Wq : (m == 1) ? Wk : Wv;
  const float* bi = (m == 0) ? bq : (m == 1) ? bk : bv;
#pragma unroll
  for (int ot = 0; ot < 2; ++ot) {
    const float* wrow = W + (ot * 32 + q31) * 64 + hi * 8;
    short8 wa0, wa1, wa2, wa3;
    {
      short8 t;
#pragma unroll
      for (int jj = 0; jj < 8; ++jj) t[jj] = (short)f2bf(wrow[jj]);
      wa0 = t;
#pragma unroll
      for (int jj = 0; jj < 8; ++jj) t[jj] = (short)f2bf(wrow[16 + jj]);
      wa1 = t;
#pragma unroll
      for (int jj = 0; jj < 8; ++jj) t[jj] = (short)f2bf(wrow[32 + jj]);
      wa2 = t;
#pragma unroll
      for (int jj = 0; jj < 8; ++jj) t[jj] = (short)f2bf(wrow[48 + jj]);
      wa3 = t;
    }
    f32x16 acc = MFMA32(wa0, xb[0], Z0);
    acc = MFMA32(wa1, xb[1], acc);
    acc = MFMA32(wa2, xb[2], acc);
    acc = MFMA32(wa3, xb[3], acc);

    if (m == 0) {
      unsigned short* dst = qo + ((size_t)b * N_ + tok) * 64;
#pragma unroll
      for (int g = 0; g < 4; ++g) {
        const int ob = 8 * g + 4 * hi + 32 * ot;
        short4v res;
#pragma unroll
        for (int i = 0; i < 4; ++i)
          res[i] = (short)f2bf((acc[4 * g + i] + bi[ob + i]) * sc);
        *(short4v*)(dst + ob) = res;
      }
    } else if (m == 1) {
      const int T = tok >> 5;
      unsigned short* kb_ = kf + (size_t)b * N_ * 64;
#pragma unroll
      for (int g = 0; g < 4; ++g) {
        const int ob = 8 * g + 4 * hi + 32 * ot;
        const int f = ob >> 4;
        const int l = (tok & 31) + 32 * ((ob >> 3) & 1);
        short4v res;
#pragma unroll
        for (int i = 0; i < 4; ++i)
          res[i] = (short)f2bf(acc[4 * g + i] + bi[ob + i]);
        *(short4v*)(kb_ + ((size_t)T * 4 + f) * 512 + l * 8 + (ob & 7)) = res;
      }
    } else {
      const int piece = (tok >> 5) * 4 + ot * 2 + ((tok >> 4) & 1);
      const int jv = (tok & 3) | (((tok >> 3) & 1) << 2);
      const int lb32 = 32 * ((tok >> 2) & 1);
      unsigned short* vbase = vf + (size_t)b * N_ * 64 + (size_t)piece * 512 + jv;
#pragma unroll
      for (int r = 0; r < 16; ++r) {
        const int o31 = (r & 3) + 8 * (r >> 2) + 4 * hi;
        vbase[(o31 + lb32) * 8] = f2bf(acc[r] + bi[o31 + 32 * ot]);
      }
    }
  }
}

// ---------------- Flash attention: 2 q-blocks/wave, 4 tiles/barrier, 2-stream ILP ----------------
#define GLDS(SRC, DST) \
  __builtin_amdgcn_global_load_lds( \
      (const __attribute__((address_space(1))) unsigned int*)(SRC), \
      (__attribute__((address_space(3))) unsigned int*)(DST), 16, 0, 0)

#define STAGE1(SET, SLOT, T) { \
  GLDS(kb + (size_t)(T) * 2048 + w * 512 + lane * 8, &lK[SET][SLOT][w * 512]); \
  GLDS(vb + (size_t)(T) * 2048 + w * 512 + lane * 8, &lV[SET][SLOT][w * 512]); \
}

#define STAGE4(SET, T) { \
  STAGE1(SET, 0, (T));     STAGE1(SET, 1, (T) + 1); \
  STAGE1(SET, 2, (T) + 2); STAGE1(SET, 3, (T) + 3); \
}

#define LDSK(KF, SET, P) { \
  const unsigned short* kr_ = &lK[SET][P][lane * 8]; \
  KF##0 = *(const short8*)(kr_);        KF##1 = *(const short8*)(kr_ + 512); \
  KF##2 = *(const short8*)(kr_ + 1024); KF##3 = *(const short8*)(kr_ + 1536); }

#define LDSV(VF, SET, P) { \
  const unsigned short* vr_ = &lV[SET][P][lane * 8]; \
  VF##0 = *(const short8*)(vr_);        VF##1 = *(const short8*)(vr_ + 512); \
  VF##2 = *(const short8*)(vr_ + 1024); VF##3 = *(const short8*)(vr_ + 1536); }

#define S_PHASE(S, KF, QF) do { \
  S = MFMA32(KF##0, QF##0, Z0); \
  S = MFMA32(KF##1, QF##1, S); \
  S = MFMA32(KF##2, QF##2, S); \
  S = MFMA32(KF##3, QF##3, S); \
} while (0)

#define SMPV(S, VF, O0, O1, LS) do { \
  _Pragma("unroll") \
  for (int r_ = 0; r_ < 16; ++r_) S[r_] = __builtin_amdgcn_exp2f(S[r_]); \
  const short8 P0 = __builtin_bit_cast(short8, \
      (i32x4){pk2t(S[0], S[1]), pk2t(S[2], S[3]), pk2t(S[4], S[5]), pk2t(S[6], S[7])}); \
  const short8 P1 = __builtin_bit_cast(short8, \
      (i32x4){pk2t(S[8], S[9]), pk2t(S[10], S[11]), pk2t(S[12], S[13]), pk2t(S[14], S[15])}); \
  LS = MFMA32(ONES, P0, LS); LS = MFMA32(ONES, P1, LS); \
  O0 = MFMA32(VF##0, P0, O0); O0 = MFMA32(VF##1, P1, O0); \
  O1 = MFMA32(VF##2, P0, O1); O1 = MFMA32(VF##3, P1, O1); \
} while (0)

__global__ __launch_bounds__(256, 2) void flash_attn2(
    const unsigned short* __restrict__ q,
    const unsigned short* __restrict__ kf,
    const unsigned short* __restrict__ vf,
    float* __restrict__ out,
    unsigned short* __restrict__ po, float* __restrict__ pl,
    int nsplit, int tiles) {
  const int b = blockIdx.x & 7;        // batch -> XCD pinning (L2 locality)
  const int j = blockIdx.x >> 3;
  const int w = threadIdx.x >> 6;
  const int item = j * 4 + w;          // [0, 64*nsplit); 4 waves of a block
  const int p = item & 63;             //   share split, consecutive q-pair
  const int split = item >> 6;
  const int lane = threadIdx.x & 63;
  const int q31 = lane & 31;
  const int hi = lane >> 5;

  __shared__ __align__(16) unsigned short lK[2][4][2048];  // 2 sets x 4-tile groups
  __shared__ __align__(16) unsigned short lV[2][4][2048];  // 64KB total

  // Two Q fragment sets: rows [p*64, p*64+32) and [p*64+32, p*64+64)
  const unsigned short* qpA = q + ((size_t)b * N_ + p * 64 + q31) * 64 + hi * 8;
  short8 qfA0 = *(const short8*)(qpA);
  short8 qfA1 = *(const short8*)(qpA + 16);
  short8 qfA2 = *(const short8*)(qpA + 32);
  short8 qfA3 = *(const short8*)(qpA + 48);
  const unsigned short* qpB = qpA + (size_t)32 * 64;
  short8 qfB0 = *(const short8*)(qpB);
  short8 qfB1 = *(const short8*)(qpB + 16);
  short8 qfB2 = *(const short8*)(qpB + 32);
  short8 qfB3 = *(const short8*)(qpB + 48);

  const short one_ = (short)0x3F80;  // bf16 1.0
  const short8 ONES = (short8){one_, one_, one_, one_, one_, one_, one_, one_};
  const f32x16 Z0 = {0.f,0.f,0.f,0.f,0.f,0.f,0.f,0.f,0.f,0.f,0.f,0.f,0.f,0.f,0.f,0.f};

  const unsigned short* kb = kf + (size_t)b * N_ * 64;
  const unsigned short* vb = vf + (size_t)b * N_ * 64;

  f32x16 o0A = Z0, o1A = Z0, lsA = Z0;
  f32x16 o0B = Z0, o1B = Z0, lsB = Z0;
  f32x16 sA, sB;

  short8 kA0, kA1, kA2, kA3;
  short8 vA0, vA1, vA2, vA3;

  const int t0 = split * tiles, t1 = t0 + tiles;  // tiles % 4 == 0 (32 at S=4)
  STAGE4(0, t0);
  __syncthreads();  // pre-barrier vmcnt(0) drain completes the stage
  for (int t = t0; t < t1; t += 4) {
    const int cur = ((t - t0) >> 2) & 1;
    if (t + 4 < t1) STAGE4(cur ^ 1, t + 4);  // in flight under this group
#pragma unroll
    for (int P = 0; P < 4; ++P) {
      LDSK(kA, cur, P);
      LDSV(vA, cur, P);
      S_PHASE(sA, kA, qfA);   // both score chains issue back-to-back:
      S_PHASE(sB, kA, qfB);   //   B's MFMA chain completes under A's softmax
      SMPV(sA, vA, o0A, o1A, lsA);
      SMPV(sB, vA, o0B, o1B, lsB);
    }
    __syncthreads();  // all waves done with cur; staged cur^1 drained
  }

  const int nA = p * 64 + q31;
  const int nB = nA + 32;
  if (nsplit == 1) {
    const float invA = 1.f / lsA[0], invB = 1.f / lsB[0];
    float* ob = out + (size_t)b * 64 * N_;
#pragma unroll
    for (int r_ = 0; r_ < 16; ++r_) {
      const int cl = (r_ & 3) + 8 * (r_ >> 2) + 4 * hi;
      ob[(size_t)cl * N_ + nA] = o0A[r_] * invA;
      ob[(size_t)(cl + 32) * N_ + nA] = o1A[r_] * invA;
      ob[(size_t)cl * N_ + nB] = o0B[r_] * invB;
      ob[(size_t)(cl + 32) * N_ + nB] = o1B[r_] * invB;
    }
  } else {
    // partials: po[split][b][c][n] unnormalized bf16; pl[split][b][n] fp32
    unsigned short* pr = po + ((size_t)(split * B_ + b) * 64) * N_;
#pragma unroll
    for (int r_ = 0; r_ < 16; ++r_) {
      const int cl = (r_ & 3) + 8 * (r_ >> 2) + 4 * hi;
      pr[(size_t)cl * N_ + nA] = f2bf(o0A[r_]);
      pr[(size_t)(cl + 32) * N_ + nA] = f2bf(o1A[r_]);
      pr[(size_t)cl * N_ + nB] = f2bf(o0B[r_]);
      pr[(size_t)(cl + 32) * N_ + nB] = f2bf(o1B[r_]);
    }
    if (hi == 0) {
      pl[(size_t)(split * B_ + b) * N_ + nA] = lsA[0];
      pl[(size_t)(split * B_ + b) * N_ + nB] = lsB[0];
    }
  }
}

// ---------------- Combine partials: plain sum, 2-n vectorized (r21) ----------------
template <int NS>
__global__ __launch_bounds__(256) void combine_k(
    const unsigned short* __restrict__ po, const float* __restrict__ pl,
    float* __restrict__ out) {
  const int n2 = (blockIdx.x * 256 + threadIdx.x) * 2;  // grid.x = N_/512
  const int c0 = blockIdx.y * 8;                        // grid.y = 8
  const int b = blockIdx.z;
  const size_t sb = (size_t)B_ * N_;

  float l0 = 0.f, l1 = 0.f;
#pragma unroll
  for (int s = 0; s < NS; ++s) {
    const float2 pv = *(const float2*)(pl + s * sb + (size_t)b * N_ + n2);
    l0 += pv.x; l1 += pv.y;
  }
  const float inv0 = 1.f / l0, inv1 = 1.f / l1;

#pragma unroll
  for (int cc = 0; cc < 8; ++cc) {
    float a0 = 0.f, a1 = 0.f;
#pragma unroll
    for (int s = 0; s < NS; ++s) {
      const unsigned v = *(const unsigned*)(
          po + ((size_t)(s * B_ + b) * 64 + c0 + cc) * N_ + n2);
      a0 += __uint_as_float(v << 16);
      a1 += __uint_as_float(v & 0xFFFF0000u);
    }
    float2 r;
    r.x = a0 * inv0; r.y = a1 * inv1;
    *(float2*)(out + ((size_t)b * 64 + c0 + cc) * N_ + n2) = r;
  }
}

extern "C" void kernel_launch(void* const* d_in, const int* in_sizes, int n_in,
                              void* d_out, int out_size, void* d_ws, size_t ws_size,
                              hipStream_t stream) {
  const float* x  = (const float*)d_in[0];
  const float* Wq = (const float*)d_in[1];
  const float* bq = (const float*)d_in[2];
  const float* Wk = (const float*)d_in[3];
  const float* bk = (const float*)d_in[4];
  const float* Wv = (const float*)d_in[5];
  const float* bv = (const float*)d_in[6];
  float* out = (float*)d_out;

  unsigned short* qws = (unsigned short*)d_ws;          // [B][N][64] bf16 row-major (scaled)
  unsigned short* kws = qws + (size_t)B_ * N_ * 64;     // [B][128][4][64][8] bf16 fragments
  unsigned short* vws = kws + (size_t)B_ * N_ * 64;     // [B][128][4][64][8] bf16 fragments

  const size_t qkv_bytes = (size_t)3 * B_ * N_ * 64 * 2;                          // 12 MB
  const size_t per_split = (size_t)B_ * N_ * 64 * 2 + (size_t)B_ * N_ * 4;        // 4.125 MB

  // S=4 (r24/r26 best; r25 showed S=8 regresses — residency is VGPR-capped).
  int S = 1;
  if (ws_size >= qkv_bytes + 4 * per_split) S = 4;
  else if (ws_size >= qkv_bytes + 2 * per_split) S = 2;

  unsigned short* po = (unsigned short*)((char*)d_ws + qkv_bytes);  // [S][B][64][N] bf16
  float* pl = (float*)(po + (size_t)S * B_ * N_ * 64);              // [S][B][N] fp32

  qkv_mfma<<<dim3(N_ / 128, 3, B_), 256, 0, stream>>>(
      x, Wq, bq, Wk, bk, Wv, bv, qws, kws, vws);

  flash_attn2<<<128 * S, 256, 0, stream>>>(qws, kws, vws, out, po, pl, S, 128 / S);

  if (S == 4)      combine_k<4><<<dim3(N_ / 512, 8, B_), 256, 0, stream>>>(po, pl, out);
  else if (S == 2) combine_k<2><<<dim3(N_ / 512, 8, B_), 256, 0, stream>>>(po, pl, out);
}

// Round 28
// 62.082 us; speedup vs baseline: 1.0482x; 1.0035x over previous
//
#include <hip/hip_runtime.h>
#include <stdint.h>

typedef __attribute__((ext_vector_type(8))) short short8;
typedef __attribute__((ext_vector_type(4))) short short4v;
typedef __attribute__((ext_vector_type(4))) float f32x4;
typedef __attribute__((ext_vector_type(16))) float f32x16;
typedef __attribute__((ext_vector_type(4))) int i32x4;

#define B_ 8
#define C_ 64
#define N_ 4096

__device__ __forceinline__ unsigned short f2bf(float f) {
  unsigned int u = __float_as_uint(f);
  u = (u + 0x7fffu + ((u >> 16) & 1u)) >> 16;
  return (unsigned short)u;
}
// P-pack: TRUNCATING bf16 pair -> dword. 1 v_perm_b32 (r19-verified).
__device__ __forceinline__ int pk2t(float lo, float hi2) {
  return (int)__builtin_amdgcn_perm(__float_as_uint(hi2), __float_as_uint(lo),
                                    0x07060302u);
}

// Session journal: r11 fragment K/V WIN (137->56). r18 LDS tile-share WIN.
// r19 MFMA l-sum WIN. r20 2-tiles/barrier WIN. r22 qkv MFMA WIN. r24
// 2 q-blocks/wave WIN. r26 4-tiles/barrier WIN (62.4). r27 explicit 2-stream
// ILP NEUTRAL (compiler already overlapped). r28: T5 s_setprio(1/0) around
// MFMA clusters (guide m191: +4-7% attn when waves have role diversity —
// our 2 independent blocks/CU qualify; zero-risk hint). If neutral, the
// structure is at its chain-latency floor (~70% issue, no pipe saturated).
// Banned: v_permlane32_swap_b32, v_cvt_pk_bf16_f32, lb waves beyond live set.
//
// Fragment buffers (shorts): [B][128 tiles][4 insts][64 lanes][8]
//   K: kf[b][T][f][l][j] = K[T*32+(l&31)][f*16 + (l>>5)*8 + j]
//   V: vf[b][T][g][l][j] = Vt[32*(g>>1)+(l&31)][slot T*32+(g&1)*16+(l>>5)*8+j]
//      where Vt[c][s] = v[c][sigma(s)], sigma = swap bits 2<->3 (r9-verified).

#define MFMA32(A, B, C) __builtin_amdgcn_mfma_f32_32x32x16_bf16(A, B, C, 0, 0, 0)

// ---------------- QKV projection via MFMA (byte-identical to r23-r27) ----------------
__global__ __launch_bounds__(256) void qkv_mfma(
    const float* __restrict__ x,
    const float* __restrict__ Wq, const float* __restrict__ bq,
    const float* __restrict__ Wk, const float* __restrict__ bk,
    const float* __restrict__ Wv, const float* __restrict__ bv,
    unsigned short* __restrict__ qo, unsigned short* __restrict__ kf,
    unsigned short* __restrict__ vf) {
  const int w = threadIdx.x >> 6;
  const int lane = threadIdx.x & 63;
  const int q31 = lane & 31;
  const int hi = lane >> 5;
  const int m = blockIdx.y;   // 0=q, 1=k, 2=v
  const int b = blockIdx.z;
  const int tok = blockIdx.x * 128 + w * 32 + q31;

  const f32x16 Z0 = {0.f,0.f,0.f,0.f,0.f,0.f,0.f,0.f,0.f,0.f,0.f,0.f,0.f,0.f,0.f,0.f};
  const float sc = 0.18033688011112042f;  // (1/sqrt(64))*log2(e), folded into Q

  short8 xb[4];
  const float* xcol = x + (size_t)b * C_ * N_ + tok;
#pragma unroll
  for (int ks = 0; ks < 4; ++ks) {
    short8 t;
#pragma unroll
    for (int jj = 0; jj < 8; ++jj)
      t[jj] = (short)f2bf(xcol[(size_t)(ks * 16 + hi * 8 + jj) * N_]);
    xb[ks] = t;
  }

  const float* W = (m == 0) ? Wq : (m == 1) ? Wk : Wv;
  const float* bi = (m == 0) ? bq : (m == 1) ? bk : bv;
#pragma unroll
  for (int ot = 0; ot < 2; ++ot) {
    const float* wrow = W + (ot * 32 + q31) * 64 + hi * 8;
    short8 wa0, wa1, wa2, wa3;
    {
      short8 t;
#pragma unroll
      for (int jj = 0; jj < 8; ++jj) t[jj] = (short)f2bf(wrow[jj]);
      wa0 = t;
#pragma unroll
      for (int jj = 0; jj < 8; ++jj) t[jj] = (short)f2bf(wrow[16 + jj]);
      wa1 = t;
#pragma unroll
      for (int jj = 0; jj < 8; ++jj) t[jj] = (short)f2bf(wrow[32 + jj]);
      wa2 = t;
#pragma unroll
      for (int jj = 0; jj < 8; ++jj) t[jj] = (short)f2bf(wrow[48 + jj]);
      wa3 = t;
    }
    f32x16 acc = MFMA32(wa0, xb[0], Z0);
    acc = MFMA32(wa1, xb[1], acc);
    acc = MFMA32(wa2, xb[2], acc);
    acc = MFMA32(wa3, xb[3], acc);

    if (m == 0) {
      unsigned short* dst = qo + ((size_t)b * N_ + tok) * 64;
#pragma unroll
      for (int g = 0; g < 4; ++g) {
        const int ob = 8 * g + 4 * hi + 32 * ot;
        short4v res;
#pragma unroll
        for (int i = 0; i < 4; ++i)
          res[i] = (short)f2bf((acc[4 * g + i] + bi[ob + i]) * sc);
        *(short4v*)(dst + ob) = res;
      }
    } else if (m == 1) {
      const int T = tok >> 5;
      unsigned short* kb_ = kf + (size_t)b * N_ * 64;
#pragma unroll
      for (int g = 0; g < 4; ++g) {
        const int ob = 8 * g + 4 * hi + 32 * ot;
        const int f = ob >> 4;
        const int l = (tok & 31) + 32 * ((ob >> 3) & 1);
        short4v res;
#pragma unroll
        for (int i = 0; i < 4; ++i)
          res[i] = (short)f2bf(acc[4 * g + i] + bi[ob + i]);
        *(short4v*)(kb_ + ((size_t)T * 4 + f) * 512 + l * 8 + (ob & 7)) = res;
      }
    } else {
      const int piece = (tok >> 5) * 4 + ot * 2 + ((tok >> 4) & 1);
      const int jv = (tok & 3) | (((tok >> 3) & 1) << 2);
      const int lb32 = 32 * ((tok >> 2) & 1);
      unsigned short* vbase = vf + (size_t)b * N_ * 64 + (size_t)piece * 512 + jv;
#pragma unroll
      for (int r = 0; r < 16; ++r) {
        const int o31 = (r & 3) + 8 * (r >> 2) + 4 * hi;
        vbase[(o31 + lb32) * 8] = f2bf(acc[r] + bi[o31 + 32 * ot]);
      }
    }
  }
}

// ---------------- Flash attention: r27 structure + T5 setprio around MFMA ----------------
#define GLDS(SRC, DST) \
  __builtin_amdgcn_global_load_lds( \
      (const __attribute__((address_space(1))) unsigned int*)(SRC), \
      (__attribute__((address_space(3))) unsigned int*)(DST), 16, 0, 0)

#define STAGE1(SET, SLOT, T) { \
  GLDS(kb + (size_t)(T) * 2048 + w * 512 + lane * 8, &lK[SET][SLOT][w * 512]); \
  GLDS(vb + (size_t)(T) * 2048 + w * 512 + lane * 8, &lV[SET][SLOT][w * 512]); \
}

#define STAGE4(SET, T) { \
  STAGE1(SET, 0, (T));     STAGE1(SET, 1, (T) + 1); \
  STAGE1(SET, 2, (T) + 2); STAGE1(SET, 3, (T) + 3); \
}

#define LDSK(KF, SET, P) { \
  const unsigned short* kr_ = &lK[SET][P][lane * 8]; \
  KF##0 = *(const short8*)(kr_);        KF##1 = *(const short8*)(kr_ + 512); \
  KF##2 = *(const short8*)(kr_ + 1024); KF##3 = *(const short8*)(kr_ + 1536); }

#define LDSV(VF, SET, P) { \
  const unsigned short* vr_ = &lV[SET][P][lane * 8]; \
  VF##0 = *(const short8*)(vr_);        VF##1 = *(const short8*)(vr_ + 512); \
  VF##2 = *(const short8*)(vr_ + 1024); VF##3 = *(const short8*)(vr_ + 1536); }

#define S_PHASE(S, KF, QF) do { \
  S = MFMA32(KF##0, QF##0, Z0); \
  S = MFMA32(KF##1, QF##1, S); \
  S = MFMA32(KF##2, QF##2, S); \
  S = MFMA32(KF##3, QF##3, S); \
} while (0)

#define SMPV(S, VF, O0, O1, LS) do { \
  _Pragma("unroll") \
  for (int r_ = 0; r_ < 16; ++r_) S[r_] = __builtin_amdgcn_exp2f(S[r_]); \
  const short8 P0 = __builtin_bit_cast(short8, \
      (i32x4){pk2t(S[0], S[1]), pk2t(S[2], S[3]), pk2t(S[4], S[5]), pk2t(S[6], S[7])}); \
  const short8 P1 = __builtin_bit_cast(short8, \
      (i32x4){pk2t(S[8], S[9]), pk2t(S[10], S[11]), pk2t(S[12], S[13]), pk2t(S[14], S[15])}); \
  __builtin_amdgcn_s_setprio(1); \
  LS = MFMA32(ONES, P0, LS); LS = MFMA32(ONES, P1, LS); \
  O0 = MFMA32(VF##0, P0, O0); O0 = MFMA32(VF##1, P1, O0); \
  O1 = MFMA32(VF##2, P0, O1); O1 = MFMA32(VF##3, P1, O1); \
  __builtin_amdgcn_s_setprio(0); \
} while (0)

__global__ __launch_bounds__(256, 2) void flash_attn2(
    const unsigned short* __restrict__ q,
    const unsigned short* __restrict__ kf,
    const unsigned short* __restrict__ vf,
    float* __restrict__ out,
    unsigned short* __restrict__ po, float* __restrict__ pl,
    int nsplit, int tiles) {
  const int b = blockIdx.x & 7;        // batch -> XCD pinning (L2 locality)
  const int j = blockIdx.x >> 3;
  const int w = threadIdx.x >> 6;
  const int item = j * 4 + w;          // [0, 64*nsplit); 4 waves of a block
  const int p = item & 63;             //   share split, consecutive q-pair
  const int split = item >> 6;
  const int lane = threadIdx.x & 63;
  const int q31 = lane & 31;
  const int hi = lane >> 5;

  __shared__ __align__(16) unsigned short lK[2][4][2048];  // 2 sets x 4-tile groups
  __shared__ __align__(16) unsigned short lV[2][4][2048];  // 64KB total

  // Two Q fragment sets: rows [p*64, p*64+32) and [p*64+32, p*64+64)
  const unsigned short* qpA = q + ((size_t)b * N_ + p * 64 + q31) * 64 + hi * 8;
  short8 qfA0 = *(const short8*)(qpA);
  short8 qfA1 = *(const short8*)(qpA + 16);
  short8 qfA2 = *(const short8*)(qpA + 32);
  short8 qfA3 = *(const short8*)(qpA + 48);
  const unsigned short* qpB = qpA + (size_t)32 * 64;
  short8 qfB0 = *(const short8*)(qpB);
  short8 qfB1 = *(const short8*)(qpB + 16);
  short8 qfB2 = *(const short8*)(qpB + 32);
  short8 qfB3 = *(const short8*)(qpB + 48);

  const short one_ = (short)0x3F80;  // bf16 1.0
  const short8 ONES = (short8){one_, one_, one_, one_, one_, one_, one_, one_};
  const f32x16 Z0 = {0.f,0.f,0.f,0.f,0.f,0.f,0.f,0.f,0.f,0.f,0.f,0.f,0.f,0.f,0.f,0.f};

  const unsigned short* kb = kf + (size_t)b * N_ * 64;
  const unsigned short* vb = vf + (size_t)b * N_ * 64;

  f32x16 o0A = Z0, o1A = Z0, lsA = Z0;
  f32x16 o0B = Z0, o1B = Z0, lsB = Z0;
  f32x16 sA, sB;

  short8 kA0, kA1, kA2, kA3;
  short8 vA0, vA1, vA2, vA3;

  const int t0 = split * tiles, t1 = t0 + tiles;  // tiles % 4 == 0 (32 at S=4)
  STAGE4(0, t0);
  __syncthreads();  // pre-barrier vmcnt(0) drain completes the stage
  for (int t = t0; t < t1; t += 4) {
    const int cur = ((t - t0) >> 2) & 1;
    if (t + 4 < t1) STAGE4(cur ^ 1, t + 4);  // in flight under this group
#pragma unroll
    for (int P = 0; P < 4; ++P) {
      LDSK(kA, cur, P);
      LDSV(vA, cur, P);
      __builtin_amdgcn_s_setprio(1);
      S_PHASE(sA, kA, qfA);   // score clusters at raised priority (T5)
      S_PHASE(sB, kA, qfB);
      __builtin_amdgcn_s_setprio(0);
      SMPV(sA, vA, o0A, o1A, lsA);
      SMPV(sB, vA, o0B, o1B, lsB);
    }
    __syncthreads();  // all waves done with cur; staged cur^1 drained
  }

  const int nA = p * 64 + q31;
  const int nB = nA + 32;
  if (nsplit == 1) {
    const float invA = 1.f / lsA[0], invB = 1.f / lsB[0];
    float* ob = out + (size_t)b * 64 * N_;
#pragma unroll
    for (int r_ = 0; r_ < 16; ++r_) {
      const int cl = (r_ & 3) + 8 * (r_ >> 2) + 4 * hi;
      ob[(size_t)cl * N_ + nA] = o0A[r_] * invA;
      ob[(size_t)(cl + 32) * N_ + nA] = o1A[r_] * invA;
      ob[(size_t)cl * N_ + nB] = o0B[r_] * invB;
      ob[(size_t)(cl + 32) * N_ + nB] = o1B[r_] * invB;
    }
  } else {
    // partials: po[split][b][c][n] unnormalized bf16; pl[split][b][n] fp32
    unsigned short* pr = po + ((size_t)(split * B_ + b) * 64) * N_;
#pragma unroll
    for (int r_ = 0; r_ < 16; ++r_) {
      const int cl = (r_ & 3) + 8 * (r_ >> 2) + 4 * hi;
      pr[(size_t)cl * N_ + nA] = f2bf(o0A[r_]);
      pr[(size_t)(cl + 32) * N_ + nA] = f2bf(o1A[r_]);
      pr[(size_t)cl * N_ + nB] = f2bf(o0B[r_]);
      pr[(size_t)(cl + 32) * N_ + nB] = f2bf(o1B[r_]);
    }
    if (hi == 0) {
      pl[(size_t)(split * B_ + b) * N_ + nA] = lsA[0];
      pl[(size_t)(split * B_ + b) * N_ + nB] = lsB[0];
    }
  }
}

// ---------------- Combine partials: plain sum, 2-n vectorized (r21) ----------------
template <int NS>
__global__ __launch_bounds__(256) void combine_k(
    const unsigned short* __restrict__ po, const float* __restrict__ pl,
    float* __restrict__ out) {
  const int n2 = (blockIdx.x * 256 + threadIdx.x) * 2;  // grid.x = N_/512
  const int c0 = blockIdx.y * 8;                        // grid.y = 8
  const int b = blockIdx.z;
  const size_t sb = (size_t)B_ * N_;

  float l0 = 0.f, l1 = 0.f;
#pragma unroll
  for (int s = 0; s < NS; ++s) {
    const float2 pv = *(const float2*)(pl + s * sb + (size_t)b * N_ + n2);
    l0 += pv.x; l1 += pv.y;
  }
  const float inv0 = 1.f / l0, inv1 = 1.f / l1;

#pragma unroll
  for (int cc = 0; cc < 8; ++cc) {
    float a0 = 0.f, a1 = 0.f;
#pragma unroll
    for (int s = 0; s < NS; ++s) {
      const unsigned v = *(const unsigned*)(
          po + ((size_t)(s * B_ + b) * 64 + c0 + cc) * N_ + n2);
      a0 += __uint_as_float(v << 16);
      a1 += __uint_as_float(v & 0xFFFF0000u);
    }
    float2 r;
    r.x = a0 * inv0; r.y = a1 * inv1;
    *(float2*)(out + ((size_t)b * 64 + c0 + cc) * N_ + n2) = r;
  }
}

extern "C" void kernel_launch(void* const* d_in, const int* in_sizes, int n_in,
                              void* d_out, int out_size, void* d_ws, size_t ws_size,
                              hipStream_t stream) {
  const float* x  = (const float*)d_in[0];
  const float* Wq = (const float*)d_in[1];
  const float* bq = (const float*)d_in[2];
  const float* Wk = (const float*)d_in[3];
  const float* bk = (const float*)d_in[4];
  const float* Wv = (const float*)d_in[5];
  const float* bv = (const float*)d_in[6];
  float* out = (float*)d_out;

  unsigned short* qws = (unsigned short*)d_ws;          // [B][N][64] bf16 row-major (scaled)
  unsigned short* kws = qws + (size_t)B_ * N_ * 64;     // [B][128][4][64][8] bf16 fragments
  unsigned short* vws = kws + (size_t)B_ * N_ * 64;     // [B][128][4][64][8] bf16 fragments

  const size_t qkv_bytes = (size_t)3 * B_ * N_ * 64 * 2;                          // 12 MB
  const size_t per_split = (size_t)B_ * N_ * 64 * 2 + (size_t)B_ * N_ * 4;        // 4.125 MB

  // S=4 (r24/r26 best; r25 showed S=8 regresses — residency is VGPR/LDS-capped).
  int S = 1;
  if (ws_size >= qkv_bytes + 4 * per_split) S = 4;
  else if (ws_size >= qkv_bytes + 2 * per_split) S = 2;

  unsigned short* po = (unsigned short*)((char*)d_ws + qkv_bytes);  // [S][B][64][N] bf16
  float* pl = (float*)(po + (size_t)S * B_ * N_ * 64);              // [S][B][N] fp32

  qkv_mfma<<<dim3(N_ / 128, 3, B_), 256, 0, stream>>>(
      x, Wq, bq, Wk, bk, Wv, bv, qws, kws, vws);

  flash_attn2<<<128 * S, 256, 0, stream>>>(qws, kws, vws, out, po, pl, S, 128 / S);

  if (S == 4)      combine_k<4><<<dim3(N_ / 512, 8, B_), 256, 0, stream>>>(po, pl, out);
  else if (S == 2) combine_k<2><<<dim3(N_ / 512, 8, B_), 256, 0, stream>>>(po, pl, out);
}